// Round 14
// baseline (233.936 us; speedup 1.0000x reference)
//
#include <hip/hip_runtime.h>
#include <hip/hip_fp16.h>

#define NN 50000
#define EE 800000
#define ETOT (EE + NN)          // 850000
#define HIDD 64
#define NHEADS 4
#define FCD 160
#define OUTD 64

#define NBKT 196                // dst>>8 -> 196 buckets of 256 dst nodes
#define BSTRIDE 5120            // fixed per-bucket capacity (mean 4352, +12 sigma)
#define CHUNK 4096
#define NEBLK ((ETOT + CHUNK - 1) / CHUNK)   // 208
#define NGB   ((NN + 63) / 64)  // 782
#define NFC128 ((NN + 127) / 128)  // 391

// ---------------- CSR build: fixed-stride bucketed counting sort (3 dispatches) ----------------

__global__ void k_zero(int* __restrict__ cursor) {
    int t = threadIdx.x;
    if (t < NBKT) cursor[t] = 0;
}

__global__ __launch_bounds__(256) void k_binwrite(const int* __restrict__ ei,
                                                  int* __restrict__ cursor,
                                                  unsigned* __restrict__ binned) {
    __shared__ int hist[NBKT];
    __shared__ int sbase[NBKT];
    __shared__ int cur[NBKT];
    int t = threadIdx.x;
    for (int i = t; i < NBKT; i += 256) hist[i] = 0;
    __syncthreads();
    int base = blockIdx.x * CHUNK;
    for (int k = t; k < CHUNK; k += 256) {
        int i = base + k;
        if (i < ETOT) {
            int dst = (i < EE) ? ei[EE + i] : (i - EE);
            atomicAdd(&hist[dst >> 8], 1);
        }
    }
    __syncthreads();
    for (int b = t; b < NBKT; b += 256) {
        int c = hist[b];
        sbase[b] = b * BSTRIDE + (c ? atomicAdd(&cursor[b], c) : 0);
        cur[b] = 0;
    }
    __syncthreads();
    for (int k = t; k < CHUNK; k += 256) {
        int i = base + k;
        if (i < ETOT) {
            int src, dst;
            if (i < EE) { src = ei[i]; dst = ei[EE + i]; }
            else { src = dst = i - EE; }
            int b = dst >> 8;
            int p = atomicAdd(&cur[b], 1);
            binned[sbase[b] + p] = ((unsigned)src << 8) | (unsigned)(dst & 255);
        }
    }
}

__global__ __launch_bounds__(256) void k_csr_final(const int* __restrict__ cursor,
                                                   const unsigned* __restrict__ binned,
                                                   int* __restrict__ rowbeg,
                                                   int* __restrict__ rowend,
                                                   int* __restrict__ csrc) {
    __shared__ int hist[256];
    __shared__ int cur[256];
    __shared__ int wsum[4];
    int b = blockIdx.x;
    int t = threadIdx.x;
    int s0 = b * BSTRIDE;
    int cnt = cursor[b];
    hist[t] = 0;
    __syncthreads();
    for (int k = t; k < cnt; k += 256) {
        unsigned pr = binned[s0 + k];
        atomicAdd(&hist[pr & 255u], 1);
    }
    __syncthreads();
    int v = hist[t];
    int lane = t & 63, w = t >> 6;
    int x = v;
    #pragma unroll
    for (int off = 1; off < 64; off <<= 1) {
        int y = __shfl_up(x, off);
        if (lane >= off) x += y;
    }
    if (lane == 63) wsum[w] = x;
    __syncthreads();
    int add = 0;
    #pragma unroll
    for (int k = 0; k < 4; k++) add += (k < w) ? wsum[k] : 0;
    int excl = x + add - v;
    int n = (b << 8) + t;
    if (n < NN) {
        rowbeg[n] = s0 + excl;
        rowend[n] = s0 + excl + v;
    }
    cur[t] = s0 + excl;
    __syncthreads();
    for (int k = t; k < cnt; k += 256) {
        unsigned pr = binned[s0 + k];
        int p = atomicAdd(&cur[pr & 255u], 1);
        csrc[p] = (int)(pr >> 8);
    }
}

// ---------------- GEMM h = x@W (fp32 compute, fp16 store) + scores ----------------

template<int FIN>
__global__ __launch_bounds__(256) void k_gemm_scores(
        const float* __restrict__ x, const float* __restrict__ W,
        const float* __restrict__ a_src, const float* __restrict__ a_dst,
        __half* __restrict__ h, float* __restrict__ ssrc, float* __restrict__ sdst) {
    __shared__ float wl[64 * 64];       // 16 KB
    __shared__ float xt[64][68];        // 17.4 KB
    int t = threadIdx.x;
    int nb = blockIdx.x * 64;
    int qg = t & 15, ng = t >> 4;
    float acc[4][4] = {};
    const float4* wl4 = (const float4*)wl;

    #pragma unroll
    for (int p = 0; p < FIN / 64; p++) {
        if (p) __syncthreads();
        for (int i = t; i < 64 * 64 / 4; i += 256)
            ((float4*)wl)[i] = ((const float4*)W)[p * 1024 + i];
        #pragma unroll
        for (int r = 0; r < 4; r++) {
            int idx = t + r * 256;
            int node = idx & 63, kq = idx >> 6;
            int n = nb + node;
            float4 v = make_float4(0.f, 0.f, 0.f, 0.f);
            if (n < NN) v = *(const float4*)(x + (size_t)n * FIN + p * 64 + kq * 4);
            xt[kq * 4 + 0][node] = v.x;
            xt[kq * 4 + 1][node] = v.y;
            xt[kq * 4 + 2][node] = v.z;
            xt[kq * 4 + 3][node] = v.w;
        }
        __syncthreads();
        #pragma unroll 4
        for (int k = 0; k < 64; k++) {
            float4 wv = wl4[k * 16 + qg];
            float4 xv = *(const float4*)&xt[k][ng * 4];
            acc[0][0] += xv.x * wv.x; acc[0][1] += xv.x * wv.y;
            acc[0][2] += xv.x * wv.z; acc[0][3] += xv.x * wv.w;
            acc[1][0] += xv.y * wv.x; acc[1][1] += xv.y * wv.y;
            acc[1][2] += xv.y * wv.z; acc[1][3] += xv.y * wv.w;
            acc[2][0] += xv.z * wv.x; acc[2][1] += xv.z * wv.y;
            acc[2][2] += xv.z * wv.z; acc[2][3] += xv.z * wv.w;
            acc[3][0] += xv.w * wv.x; acc[3][1] += xv.w * wv.y;
            acc[3][2] += xv.w * wv.z; acc[3][3] += xv.w * wv.w;
        }
    }

    #pragma unroll
    for (int r = 0; r < 4; r++) {
        int n = nb + ng * 4 + r;
        if (n < NN) {
            union { __half2 h2[2]; uint2 u; } pk;
            pk.h2[0] = __floats2half2_rn(acc[r][0], acc[r][1]);
            pk.h2[1] = __floats2half2_rn(acc[r][2], acc[r][3]);
            *(uint2*)(h + (size_t)n * HIDD + qg * 4) = pk.u;
        }
    }

    float as0 = a_src[qg * 4 + 0], as1 = a_src[qg * 4 + 1];
    float as2 = a_src[qg * 4 + 2], as3 = a_src[qg * 4 + 3];
    float ad0 = a_dst[qg * 4 + 0], ad1 = a_dst[qg * 4 + 1];
    float ad2 = a_dst[qg * 4 + 2], ad3 = a_dst[qg * 4 + 3];
    float vs[4], vd[4];
    #pragma unroll
    for (int r = 0; r < 4; r++) {
        vs[r] = acc[r][0] * as0 + acc[r][1] * as1 + acc[r][2] * as2 + acc[r][3] * as3;
        vd[r] = acc[r][0] * ad0 + acc[r][1] * ad1 + acc[r][2] * ad2 + acc[r][3] * ad3;
        vs[r] += __shfl_xor(vs[r], 1); vs[r] += __shfl_xor(vs[r], 2);
        vd[r] += __shfl_xor(vd[r], 1); vd[r] += __shfl_xor(vd[r], 2);
    }
    if ((qg & 3) == 0) {
        int hd = qg >> 2;
        #pragma unroll
        for (int r = 0; r < 4; r++) {
            int n = nb + ng * 4 + r;
            if (n < NN) {
                ssrc[n * NHEADS + hd] = vs[r];
                sdst[n * NHEADS + hd] = vd[r];
            }
        }
    }
}

// ---------------- aggregation: fp16 gather, 16 edges in flight per wave ----------------

__global__ __launch_bounds__(256) void k_aggr(
        const __half* __restrict__ h, const float* __restrict__ ssrc,
        const float* __restrict__ sdst, const int* __restrict__ rowbeg,
        const int* __restrict__ rowend,
        const int* __restrict__ csrc, const float* __restrict__ bias,
        float* __restrict__ out) {
    int wid  = threadIdx.x >> 6;
    int lane = threadIdx.x & 63;
    int n = blockIdx.x * 4 + wid;
    int sub = lane >> 4;            // edge subgroup 0..3
    int c4  = lane & 15;            // channel quad 0..15
    int hd  = c4 >> 2;              // head 0..3
    int beg = rowbeg[n], end = rowend[n];
    float sdh = sdst[n * NHEADS + hd];

    float4 acc = make_float4(0.f, 0.f, 0.f, 0.f);
    float z = 0.f;
    for (int cb = beg; cb < end; cb += 16) {
        #pragma unroll
        for (int o = 0; o < 4; o++) {
            int e = cb + sub + o * 4;
            if (e < end) {
                int s = csrc[e];
                float eh = ssrc[s * NHEADS + hd] + sdh;
                eh = eh > 0.f ? eh : 0.2f * eh;
                float w = __expf(eh);
                uint2 r = *(const uint2*)(h + (size_t)s * HIDD + c4 * 4);
                float2 lo = __half22float2(*(__half2*)&r.x);
                float2 hi = __half22float2(*(__half2*)&r.y);
                acc.x += lo.x * w; acc.y += lo.y * w;
                acc.z += hi.x * w; acc.w += hi.y * w;
                z += w;
            }
        }
    }
    acc.x += __shfl_xor(acc.x, 16); acc.y += __shfl_xor(acc.y, 16);
    acc.z += __shfl_xor(acc.z, 16); acc.w += __shfl_xor(acc.w, 16);
    z += __shfl_xor(z, 16);
    acc.x += __shfl_xor(acc.x, 32); acc.y += __shfl_xor(acc.y, 32);
    acc.z += __shfl_xor(acc.z, 32); acc.w += __shfl_xor(acc.w, 32);
    z += __shfl_xor(z, 32);

    if (sub == 0) {
        float inv_z = 1.0f / (z + 1e-16f);
        float4 bv = *(const float4*)(bias + c4 * 4);
        float4 o;
        o.x = acc.x * inv_z + bv.x; o.x = o.x > 0.f ? o.x : 0.f;
        o.y = acc.y * inv_z + bv.y; o.y = o.y > 0.f ? o.y : 0.f;
        o.z = acc.z * inv_z + bv.z; o.z = o.z > 0.f ? o.z : 0.f;
        o.w = acc.w * inv_z + bv.w; o.w = o.w > 0.f ? o.w : 0.f;
        *(float4*)(out + (size_t)n * HIDD + c4 * 4) = o;
    }
}

// ---------------- fused FC head: 128-node tile, deep node-blocking ----------------
// y = relu(x@W1+b1) (fp16 LDS); out = y@W2+b2.
// Phase A: thread=(qg 0..7, ng 0..31): 4 nodes x 5 quads (80 acc) — 96B LDS / 80 FMA.
// Phase B: thread=(qg 0..15, ng 0..15): 8 nodes x 1 quad (32 acc) — 32B LDS / 32 FMA.
// LDS: wl 20KB + xt[32][132] 16.5KB + y[160][136] fp16 43.5KB = 80KB -> 2 blocks/CU.

__global__ __launch_bounds__(256) void k_fc_fused(const float* __restrict__ x,
        const float* __restrict__ W1, const float* __restrict__ b1,
        const float* __restrict__ W2, const float* __restrict__ b2,
        float* __restrict__ out) {
    __shared__ float wl[32 * 160];      // 20 KB (== 80*64 in phase B)
    __shared__ float xt[32][132];       // 16.5 KB (rows 16B-aligned)
    __shared__ __half y[160][136];      // 43.5 KB (rows 16B-aligned)
    int t = threadIdx.x;
    int nb = blockIdx.x * 128;
    const float4* wl4 = (const float4*)wl;

    // ---- phase A: y = relu(x@W1 + b1) ----
    {
        int qg = t & 7, ng = t >> 3;    // ng 0..31, 4 nodes each
        float acc[4][5][4] = {};
        #pragma unroll
        for (int p = 0; p < 2; p++) {
            if (p) __syncthreads();
            for (int i = t; i < 32 * 160 / 4; i += 256)
                ((float4*)wl)[i] = ((const float4*)W1)[p * 32 * 40 + i];
            #pragma unroll
            for (int r = 0; r < 4; r++) {
                int idx = t + r * 256;                // 0..1023
                int node = idx & 127, kq = idx >> 7;  // kq 0..7
                int n = nb + node;
                float4 v = make_float4(0.f, 0.f, 0.f, 0.f);
                if (n < NN) v = *(const float4*)(x + (size_t)n * 64 + p * 32 + kq * 4);
                xt[kq * 4 + 0][node] = v.x;
                xt[kq * 4 + 1][node] = v.y;
                xt[kq * 4 + 2][node] = v.z;
                xt[kq * 4 + 3][node] = v.w;
            }
            __syncthreads();
            #pragma unroll 4
            for (int k = 0; k < 32; k++) {
                float4 xv = *(const float4*)&xt[k][ng * 4];
                #pragma unroll
                for (int i = 0; i < 5; i++) {
                    float4 wv = wl4[k * 40 + qg + 8 * i];
                    acc[0][i][0] += xv.x * wv.x; acc[0][i][1] += xv.x * wv.y;
                    acc[0][i][2] += xv.x * wv.z; acc[0][i][3] += xv.x * wv.w;
                    acc[1][i][0] += xv.y * wv.x; acc[1][i][1] += xv.y * wv.y;
                    acc[1][i][2] += xv.y * wv.z; acc[1][i][3] += xv.y * wv.w;
                    acc[2][i][0] += xv.z * wv.x; acc[2][i][1] += xv.z * wv.y;
                    acc[2][i][2] += xv.z * wv.z; acc[2][i][3] += xv.z * wv.w;
                    acc[3][i][0] += xv.w * wv.x; acc[3][i][1] += xv.w * wv.y;
                    acc[3][i][2] += xv.w * wv.z; acc[3][i][3] += xv.w * wv.w;
                }
            }
        }
        // bias + relu -> y (fp16, transposed for phase B)
        #pragma unroll
        for (int i = 0; i < 5; i++) {
            int j0 = (qg + 8 * i) * 4;
            float4 bv = *(const float4*)(b1 + j0);
            #pragma unroll
            for (int r = 0; r < 4; r++) {
                int node = ng * 4 + r;
                float v0 = acc[r][i][0] + bv.x; v0 = v0 > 0.f ? v0 : 0.f;
                float v1 = acc[r][i][1] + bv.y; v1 = v1 > 0.f ? v1 : 0.f;
                float v2 = acc[r][i][2] + bv.z; v2 = v2 > 0.f ? v2 : 0.f;
                float v3 = acc[r][i][3] + bv.w; v3 = v3 > 0.f ? v3 : 0.f;
                y[j0 + 0][node] = __float2half_rn(v0);
                y[j0 + 1][node] = __float2half_rn(v1);
                y[j0 + 2][node] = __float2half_rn(v2);
                y[j0 + 3][node] = __float2half_rn(v3);
            }
        }
    }
    __syncthreads();    // y complete; wl free

    // ---- phase B: out = y@W2 + b2 ----
    {
        int qg = t & 15, ng = t >> 4;   // ng 0..15, 8 nodes each
        float acc[8][4] = {};
        #pragma unroll
        for (int p = 0; p < 2; p++) {
            if (p) __syncthreads();
            for (int i = t; i < 80 * 64 / 4; i += 256)
                ((float4*)wl)[i] = ((const float4*)W2)[p * 80 * 16 + i];
            __syncthreads();
            #pragma unroll 2
            for (int k = 0; k < 80; k++) {
                float4 wv = wl4[k * 16 + qg];
                uint4 yr = *(const uint4*)&y[p * 80 + k][ng * 8];
                float2 f0 = __half22float2(*(__half2*)&yr.x);
                float2 f1 = __half22float2(*(__half2*)&yr.y);
                float2 f2 = __half22float2(*(__half2*)&yr.z);
                float2 f3 = __half22float2(*(__half2*)&yr.w);
                acc[0][0] += f0.x * wv.x; acc[0][1] += f0.x * wv.y;
                acc[0][2] += f0.x * wv.z; acc[0][3] += f0.x * wv.w;
                acc[1][0] += f0.y * wv.x; acc[1][1] += f0.y * wv.y;
                acc[1][2] += f0.y * wv.z; acc[1][3] += f0.y * wv.w;
                acc[2][0] += f1.x * wv.x; acc[2][1] += f1.x * wv.y;
                acc[2][2] += f1.x * wv.z; acc[2][3] += f1.x * wv.w;
                acc[3][0] += f1.y * wv.x; acc[3][1] += f1.y * wv.y;
                acc[3][2] += f1.y * wv.z; acc[3][3] += f1.y * wv.w;
                acc[4][0] += f2.x * wv.x; acc[4][1] += f2.x * wv.y;
                acc[4][2] += f2.x * wv.z; acc[4][3] += f2.x * wv.w;
                acc[5][0] += f2.y * wv.x; acc[5][1] += f2.y * wv.y;
                acc[5][2] += f2.y * wv.z; acc[5][3] += f2.y * wv.w;
                acc[6][0] += f3.x * wv.x; acc[6][1] += f3.x * wv.y;
                acc[6][2] += f3.x * wv.z; acc[6][3] += f3.x * wv.w;
                acc[7][0] += f3.y * wv.x; acc[7][1] += f3.y * wv.y;
                acc[7][2] += f3.y * wv.z; acc[7][3] += f3.y * wv.w;
            }
        }
        int j0 = qg * 4;
        float4 bv = *(const float4*)(b2 + j0);
        #pragma unroll
        for (int r = 0; r < 8; r++) {
            int n = nb + ng * 8 + r;
            if (n < NN) {
                float4 o;
                o.x = acc[r][0] + bv.x; o.y = acc[r][1] + bv.y;
                o.z = acc[r][2] + bv.z; o.w = acc[r][3] + bv.w;
                *(float4*)(out + (size_t)n * 64 + j0) = o;
            }
        }
    }
}

// ---------------- launch ----------------

extern "C" void kernel_launch(void* const* d_in, const int* in_sizes, int n_in,
                              void* d_out, int out_size, void* d_ws, size_t ws_size,
                              hipStream_t stream) {
    const float* x   = (const float*)d_in[0];
    const int*   ei  = (const int*)d_in[1];
    const float* W0  = (const float*)d_in[2];
    const float* as0 = (const float*)d_in[3];
    const float* ad0 = (const float*)d_in[4];
    const float* b0  = (const float*)d_in[5];
    const float* W1  = (const float*)d_in[6];
    const float* as1 = (const float*)d_in[7];
    const float* ad1 = (const float*)d_in[8];
    const float* b1  = (const float*)d_in[9];
    const float* W2  = (const float*)d_in[10];
    const float* as2 = (const float*)d_in[11];
    const float* ad2 = (const float*)d_in[12];
    const float* b2  = (const float*)d_in[13];
    const float* fw1 = (const float*)d_in[14];
    const float* fb1 = (const float*)d_in[15];
    const float* fw2 = (const float*)d_in[16];
    const float* fb2 = (const float*)d_in[17];

    float* ws     = (float*)d_ws;
    __half* h_buf = (__half*)ws;                 // N*64 halves
    float* ssrc   = ws + (size_t)NN * HIDD;      // N*4
    float* sdst   = ssrc + (size_t)NN * NHEADS;  // N*4
    float* act    = sdst + (size_t)NN * NHEADS;  // N*64
    float* fcb    = act + (size_t)NN * HIDD;     // N*160 slot (CSR scratch lives here)
    unsigned* binned = (unsigned*)fcb;                    // NBKT*BSTRIDE ~1.0M
    int*   csrc   = (int*)fcb + 2000000;                  // NBKT*BSTRIDE ~1.0M
    int*   rowbeg = (int*)fcb + 4000000;                  // NN
    int*   rowend = (int*)fcb + 4100000;                  // NN
    int*   cursor = (int*)(fcb + (size_t)NN * FCD);       // NBKT

    k_zero<<<1, 256, 0, stream>>>(cursor);
    k_binwrite<<<NEBLK, 256, 0, stream>>>(ei, cursor, binned);
    k_csr_final<<<NBKT, 256, 0, stream>>>(cursor, binned, rowbeg, rowend, csrc);

    // layer 0
    k_gemm_scores<128><<<NGB, 256, 0, stream>>>(x, W0, as0, ad0, h_buf, ssrc, sdst);
    k_aggr<<<NN / 4, 256, 0, stream>>>(h_buf, ssrc, sdst, rowbeg, rowend, csrc, b0, act);
    // layer 1
    k_gemm_scores<64><<<NGB, 256, 0, stream>>>(act, W1, as1, ad1, h_buf, ssrc, sdst);
    k_aggr<<<NN / 4, 256, 0, stream>>>(h_buf, ssrc, sdst, rowbeg, rowend, csrc, b1, act);
    // layer 2
    k_gemm_scores<64><<<NGB, 256, 0, stream>>>(act, W2, as2, ad2, h_buf, ssrc, sdst);
    k_aggr<<<NN / 4, 256, 0, stream>>>(h_buf, ssrc, sdst, rowbeg, rowend, csrc, b2, act);

    // fused FC head (128-node tile)
    k_fc_fused<<<NFC128, 256, 0, stream>>>(act, fw1, fb1, fw2, fb2, (float*)d_out);
}

// Round 15
// 222.273 us; speedup vs baseline: 1.0525x; 1.0525x over previous
//
#include <hip/hip_runtime.h>
#include <hip/hip_fp16.h>

#define NN 50000
#define EE 800000
#define ETOT (EE + NN)          // 850000
#define HIDD 64
#define NHEADS 4
#define FCD 160
#define OUTD 64

#define NBKT 196                // dst>>8 -> 196 buckets of 256 dst nodes
#define BSTRIDE 5120            // fixed per-bucket capacity (mean 4352)
#define CHUNK 4096
#define NEBLK ((ETOT + CHUNK - 1) / CHUNK)   // 208
#define NGB   ((NN + 63) / 64)  // 782
#define NFC128 ((NN + 127) / 128)  // 391

// ---------------- CSR build: fixed-stride bucketed counting sort ----------------

__global__ void k_zero(int* __restrict__ cursor) {
    int t = threadIdx.x;
    if (t < NBKT) cursor[t] = 0;
}

__global__ __launch_bounds__(256) void k_binwrite(const int* __restrict__ ei,
                                                  int* __restrict__ cursor,
                                                  unsigned* __restrict__ binned) {
    __shared__ int hist[NBKT];
    __shared__ int sbase[NBKT];
    __shared__ int cur[NBKT];
    int t = threadIdx.x;
    for (int i = t; i < NBKT; i += 256) hist[i] = 0;
    __syncthreads();
    int base = blockIdx.x * CHUNK;
    for (int k = t; k < CHUNK; k += 256) {
        int i = base + k;
        if (i < ETOT) {
            int dst = (i < EE) ? ei[EE + i] : (i - EE);
            atomicAdd(&hist[dst >> 8], 1);
        }
    }
    __syncthreads();
    for (int b = t; b < NBKT; b += 256) {
        int c = hist[b];
        sbase[b] = b * BSTRIDE + (c ? atomicAdd(&cursor[b], c) : 0);
        cur[b] = 0;
    }
    __syncthreads();
    for (int k = t; k < CHUNK; k += 256) {
        int i = base + k;
        if (i < ETOT) {
            int src, dst;
            if (i < EE) { src = ei[i]; dst = ei[EE + i]; }
            else { src = dst = i - EE; }
            int b = dst >> 8;
            int p = atomicAdd(&cur[b], 1);
            binned[sbase[b] + p] = ((unsigned)src << 8) | (unsigned)(dst & 255);
        }
    }
}

__global__ __launch_bounds__(256) void k_csr_final(const int* __restrict__ cursor,
                                                   const unsigned* __restrict__ binned,
                                                   int* __restrict__ rowbeg,
                                                   int* __restrict__ rowend,
                                                   int* __restrict__ csrc) {
    __shared__ int hist[256];
    __shared__ int cur[256];
    __shared__ int wsum[4];
    int b = blockIdx.x;
    int t = threadIdx.x;
    int s0 = b * BSTRIDE;
    int cnt = cursor[b];
    hist[t] = 0;
    __syncthreads();
    for (int k = t; k < cnt; k += 256) {
        unsigned pr = binned[s0 + k];
        atomicAdd(&hist[pr & 255u], 1);
    }
    __syncthreads();
    int v = hist[t];
    int lane = t & 63, w = t >> 6;
    int x = v;
    #pragma unroll
    for (int off = 1; off < 64; off <<= 1) {
        int y = __shfl_up(x, off);
        if (lane >= off) x += y;
    }
    if (lane == 63) wsum[w] = x;
    __syncthreads();
    int add = 0;
    #pragma unroll
    for (int k = 0; k < 4; k++) add += (k < w) ? wsum[k] : 0;
    int excl = x + add - v;
    int n = (b << 8) + t;
    if (n < NN) {
        rowbeg[n] = s0 + excl;
        rowend[n] = s0 + excl + v;
    }
    cur[t] = s0 + excl;
    __syncthreads();
    for (int k = t; k < cnt; k += 256) {
        unsigned pr = binned[s0 + k];
        int p = atomicAdd(&cur[pr & 255u], 1);
        csrc[p] = (int)(pr >> 8);
    }
}

// ---------------- GEMM h = x@W (fp32 compute, fp16 store) + scores (layer 0) ----------------

template<int FIN>
__global__ __launch_bounds__(256) void k_gemm_scores(
        const float* __restrict__ x, const float* __restrict__ W,
        const float* __restrict__ a_src, const float* __restrict__ a_dst,
        __half* __restrict__ h, float* __restrict__ ssrc, float* __restrict__ sdst) {
    __shared__ float wl[64 * 64];       // 16 KB
    __shared__ float xt[64][68];        // 17.4 KB
    int t = threadIdx.x;
    int nb = blockIdx.x * 64;
    int qg = t & 15, ng = t >> 4;
    float acc[4][4] = {};
    const float4* wl4 = (const float4*)wl;

    #pragma unroll
    for (int p = 0; p < FIN / 64; p++) {
        if (p) __syncthreads();
        for (int i = t; i < 64 * 64 / 4; i += 256)
            ((float4*)wl)[i] = ((const float4*)W)[p * 1024 + i];
        #pragma unroll
        for (int r = 0; r < 4; r++) {
            int idx = t + r * 256;
            int node = idx & 63, kq = idx >> 6;
            int n = nb + node;
            float4 v = make_float4(0.f, 0.f, 0.f, 0.f);
            if (n < NN) v = *(const float4*)(x + (size_t)n * FIN + p * 64 + kq * 4);
            xt[kq * 4 + 0][node] = v.x;
            xt[kq * 4 + 1][node] = v.y;
            xt[kq * 4 + 2][node] = v.z;
            xt[kq * 4 + 3][node] = v.w;
        }
        __syncthreads();
        #pragma unroll 4
        for (int k = 0; k < 64; k++) {
            float4 wv = wl4[k * 16 + qg];
            float4 xv = *(const float4*)&xt[k][ng * 4];
            acc[0][0] += xv.x * wv.x; acc[0][1] += xv.x * wv.y;
            acc[0][2] += xv.x * wv.z; acc[0][3] += xv.x * wv.w;
            acc[1][0] += xv.y * wv.x; acc[1][1] += xv.y * wv.y;
            acc[1][2] += xv.y * wv.z; acc[1][3] += xv.y * wv.w;
            acc[2][0] += xv.z * wv.x; acc[2][1] += xv.z * wv.y;
            acc[2][2] += xv.z * wv.z; acc[2][3] += xv.z * wv.w;
            acc[3][0] += xv.w * wv.x; acc[3][1] += xv.w * wv.y;
            acc[3][2] += xv.w * wv.z; acc[3][3] += xv.w * wv.w;
        }
    }

    #pragma unroll
    for (int r = 0; r < 4; r++) {
        int n = nb + ng * 4 + r;
        if (n < NN) {
            union { __half2 h2[2]; uint2 u; } pk;
            pk.h2[0] = __floats2half2_rn(acc[r][0], acc[r][1]);
            pk.h2[1] = __floats2half2_rn(acc[r][2], acc[r][3]);
            *(uint2*)(h + (size_t)n * HIDD + qg * 4) = pk.u;
        }
    }

    float as0 = a_src[qg * 4 + 0], as1 = a_src[qg * 4 + 1];
    float as2 = a_src[qg * 4 + 2], as3 = a_src[qg * 4 + 3];
    float ad0 = a_dst[qg * 4 + 0], ad1 = a_dst[qg * 4 + 1];
    float ad2 = a_dst[qg * 4 + 2], ad3 = a_dst[qg * 4 + 3];
    float vs[4], vd[4];
    #pragma unroll
    for (int r = 0; r < 4; r++) {
        vs[r] = acc[r][0] * as0 + acc[r][1] * as1 + acc[r][2] * as2 + acc[r][3] * as3;
        vd[r] = acc[r][0] * ad0 + acc[r][1] * ad1 + acc[r][2] * ad2 + acc[r][3] * ad3;
        vs[r] += __shfl_xor(vs[r], 1); vs[r] += __shfl_xor(vs[r], 2);
        vd[r] += __shfl_xor(vd[r], 1); vd[r] += __shfl_xor(vd[r], 2);
    }
    if ((qg & 3) == 0) {
        int hd = qg >> 2;
        #pragma unroll
        for (int r = 0; r < 4; r++) {
            int n = nb + ng * 4 + r;
            if (n < NN) {
                ssrc[n * NHEADS + hd] = vs[r];
                sdst[n * NHEADS + hd] = vd[r];
            }
        }
    }
}

// ---------------- fused aggr(L) + gemm(L+1): act stays in LDS ----------------
// 512 threads, 64-node tile. Phase 1: 8 waves x 8 nodes aggregation (16 edges
// in flight/wave) -> xt[ch][node] (+bias,relu). Phase 2: h' = act@W + scores.
// W staged before aggregation (latency hidden). LDS 33.8KB -> 4 blocks/CU,
// 32 waves/CU (same aggregation occupancy as standalone k_aggr).

__global__ __launch_bounds__(512) void k_aggr_gemm(
        const __half* __restrict__ h, const float* __restrict__ ssrc,
        const float* __restrict__ sdst, const int* __restrict__ rowbeg,
        const int* __restrict__ rowend, const int* __restrict__ csrc,
        const float* __restrict__ bias, const float* __restrict__ W,
        const float* __restrict__ a_src, const float* __restrict__ a_dst,
        __half* __restrict__ hout, float* __restrict__ ssrc_o,
        float* __restrict__ sdst_o) {
    __shared__ float wl[64 * 64];       // 16 KB
    __shared__ float xt[64][68];        // 17.4 KB
    int t = threadIdx.x;
    int nb = blockIdx.x * 64;

    // stage W early (no barrier needed until gemm)
    for (int i = t; i < 64 * 64 / 4; i += 512)
        ((float4*)wl)[i] = ((const float4*)W)[i];

    // ---- phase 1: aggregation, wave = 8 nodes sequential ----
    {
        int wid = t >> 6, lane = t & 63;
        int sub = lane >> 4, c4 = lane & 15, hd = c4 >> 2;
        #pragma unroll 1
        for (int i = 0; i < 8; i++) {
            int nl = wid * 8 + i;
            int n = nb + nl;
            float4 acc = make_float4(0.f, 0.f, 0.f, 0.f);
            float z = 0.f;
            if (n < NN) {
                int beg = rowbeg[n], end = rowend[n];
                float sdh = sdst[n * NHEADS + hd];
                for (int cb = beg; cb < end; cb += 16) {
                    #pragma unroll
                    for (int o = 0; o < 4; o++) {
                        int e = cb + sub + o * 4;
                        if (e < end) {
                            int s = csrc[e];
                            float eh = ssrc[s * NHEADS + hd] + sdh;
                            eh = eh > 0.f ? eh : 0.2f * eh;
                            float w = __expf(eh);
                            uint2 r = *(const uint2*)(h + (size_t)s * HIDD + c4 * 4);
                            float2 lo = __half22float2(*(__half2*)&r.x);
                            float2 hi = __half22float2(*(__half2*)&r.y);
                            acc.x += lo.x * w; acc.y += lo.y * w;
                            acc.z += hi.x * w; acc.w += hi.y * w;
                            z += w;
                        }
                    }
                }
            }
            acc.x += __shfl_xor(acc.x, 16); acc.y += __shfl_xor(acc.y, 16);
            acc.z += __shfl_xor(acc.z, 16); acc.w += __shfl_xor(acc.w, 16);
            z += __shfl_xor(z, 16);
            acc.x += __shfl_xor(acc.x, 32); acc.y += __shfl_xor(acc.y, 32);
            acc.z += __shfl_xor(acc.z, 32); acc.w += __shfl_xor(acc.w, 32);
            z += __shfl_xor(z, 32);
            if (sub == 0) {
                float inv_z = 1.0f / (z + 1e-16f);
                float4 bv = *(const float4*)(bias + c4 * 4);
                float v0 = acc.x * inv_z + bv.x; v0 = v0 > 0.f ? v0 : 0.f;
                float v1 = acc.y * inv_z + bv.y; v1 = v1 > 0.f ? v1 : 0.f;
                float v2 = acc.z * inv_z + bv.z; v2 = v2 > 0.f ? v2 : 0.f;
                float v3 = acc.w * inv_z + bv.w; v3 = v3 > 0.f ? v3 : 0.f;
                if (n >= NN) { v0 = v1 = v2 = v3 = 0.f; }
                xt[c4 * 4 + 0][nl] = v0;
                xt[c4 * 4 + 1][nl] = v1;
                xt[c4 * 4 + 2][nl] = v2;
                xt[c4 * 4 + 3][nl] = v3;
            }
        }
    }
    __syncthreads();    // xt + wl both ready

    // ---- phase 2: h' = act@W, scores; thread = (qg 0..15, ng 0..31): 2 nodes ----
    {
        int qg = t & 15, ng = t >> 4;
        float acc[2][4] = {};
        const float4* wl4 = (const float4*)wl;
        #pragma unroll 4
        for (int k = 0; k < 64; k++) {
            float4 wv = wl4[k * 16 + qg];
            float2 xv = *(const float2*)&xt[k][ng * 2];
            acc[0][0] += xv.x * wv.x; acc[0][1] += xv.x * wv.y;
            acc[0][2] += xv.x * wv.z; acc[0][3] += xv.x * wv.w;
            acc[1][0] += xv.y * wv.x; acc[1][1] += xv.y * wv.y;
            acc[1][2] += xv.y * wv.z; acc[1][3] += xv.y * wv.w;
        }
        #pragma unroll
        for (int r = 0; r < 2; r++) {
            int n = nb + ng * 2 + r;
            if (n < NN) {
                union { __half2 h2[2]; uint2 u; } pk;
                pk.h2[0] = __floats2half2_rn(acc[r][0], acc[r][1]);
                pk.h2[1] = __floats2half2_rn(acc[r][2], acc[r][3]);
                *(uint2*)(hout + (size_t)n * HIDD + qg * 4) = pk.u;
            }
        }
        float as0 = a_src[qg * 4 + 0], as1 = a_src[qg * 4 + 1];
        float as2 = a_src[qg * 4 + 2], as3 = a_src[qg * 4 + 3];
        float ad0 = a_dst[qg * 4 + 0], ad1 = a_dst[qg * 4 + 1];
        float ad2 = a_dst[qg * 4 + 2], ad3 = a_dst[qg * 4 + 3];
        float vs[2], vd[2];
        #pragma unroll
        for (int r = 0; r < 2; r++) {
            vs[r] = acc[r][0] * as0 + acc[r][1] * as1 + acc[r][2] * as2 + acc[r][3] * as3;
            vd[r] = acc[r][0] * ad0 + acc[r][1] * ad1 + acc[r][2] * ad2 + acc[r][3] * ad3;
            vs[r] += __shfl_xor(vs[r], 1); vs[r] += __shfl_xor(vs[r], 2);
            vd[r] += __shfl_xor(vd[r], 1); vd[r] += __shfl_xor(vd[r], 2);
        }
        if ((qg & 3) == 0) {
            int hd = qg >> 2;
            #pragma unroll
            for (int r = 0; r < 2; r++) {
                int n = nb + ng * 2 + r;
                if (n < NN) {
                    ssrc_o[n * NHEADS + hd] = vs[r];
                    sdst_o[n * NHEADS + hd] = vd[r];
                }
            }
        }
    }
}

// ---------------- final aggregation (layer 2 output -> act for FC) ----------------

__global__ __launch_bounds__(256) void k_aggr(
        const __half* __restrict__ h, const float* __restrict__ ssrc,
        const float* __restrict__ sdst, const int* __restrict__ rowbeg,
        const int* __restrict__ rowend,
        const int* __restrict__ csrc, const float* __restrict__ bias,
        float* __restrict__ out) {
    int wid  = threadIdx.x >> 6;
    int lane = threadIdx.x & 63;
    int n = blockIdx.x * 4 + wid;
    int sub = lane >> 4;
    int c4  = lane & 15;
    int hd  = c4 >> 2;
    int beg = rowbeg[n], end = rowend[n];
    float sdh = sdst[n * NHEADS + hd];

    float4 acc = make_float4(0.f, 0.f, 0.f, 0.f);
    float z = 0.f;
    for (int cb = beg; cb < end; cb += 16) {
        #pragma unroll
        for (int o = 0; o < 4; o++) {
            int e = cb + sub + o * 4;
            if (e < end) {
                int s = csrc[e];
                float eh = ssrc[s * NHEADS + hd] + sdh;
                eh = eh > 0.f ? eh : 0.2f * eh;
                float w = __expf(eh);
                uint2 r = *(const uint2*)(h + (size_t)s * HIDD + c4 * 4);
                float2 lo = __half22float2(*(__half2*)&r.x);
                float2 hi = __half22float2(*(__half2*)&r.y);
                acc.x += lo.x * w; acc.y += lo.y * w;
                acc.z += hi.x * w; acc.w += hi.y * w;
                z += w;
            }
        }
    }
    acc.x += __shfl_xor(acc.x, 16); acc.y += __shfl_xor(acc.y, 16);
    acc.z += __shfl_xor(acc.z, 16); acc.w += __shfl_xor(acc.w, 16);
    z += __shfl_xor(z, 16);
    acc.x += __shfl_xor(acc.x, 32); acc.y += __shfl_xor(acc.y, 32);
    acc.z += __shfl_xor(acc.z, 32); acc.w += __shfl_xor(acc.w, 32);
    z += __shfl_xor(z, 32);

    if (sub == 0) {
        float inv_z = 1.0f / (z + 1e-16f);
        float4 bv = *(const float4*)(bias + c4 * 4);
        float4 o;
        o.x = acc.x * inv_z + bv.x; o.x = o.x > 0.f ? o.x : 0.f;
        o.y = acc.y * inv_z + bv.y; o.y = o.y > 0.f ? o.y : 0.f;
        o.z = acc.z * inv_z + bv.z; o.z = o.z > 0.f ? o.z : 0.f;
        o.w = acc.w * inv_z + bv.w; o.w = o.w > 0.f ? o.w : 0.f;
        *(float4*)(out + (size_t)n * HIDD + c4 * 4) = o;
    }
}

// ---------------- fused FC head: 128-node tile (r14) ----------------

__global__ __launch_bounds__(256) void k_fc_fused(const float* __restrict__ x,
        const float* __restrict__ W1, const float* __restrict__ b1,
        const float* __restrict__ W2, const float* __restrict__ b2,
        float* __restrict__ out) {
    __shared__ float wl[32 * 160];      // 20 KB
    __shared__ float xt[32][132];       // 16.5 KB
    __shared__ __half y[160][136];      // 43.5 KB
    int t = threadIdx.x;
    int nb = blockIdx.x * 128;
    const float4* wl4 = (const float4*)wl;

    {
        int qg = t & 7, ng = t >> 3;
        float acc[4][5][4] = {};
        #pragma unroll
        for (int p = 0; p < 2; p++) {
            if (p) __syncthreads();
            for (int i = t; i < 32 * 160 / 4; i += 256)
                ((float4*)wl)[i] = ((const float4*)W1)[p * 32 * 40 + i];
            #pragma unroll
            for (int r = 0; r < 4; r++) {
                int idx = t + r * 256;
                int node = idx & 127, kq = idx >> 7;
                int n = nb + node;
                float4 v = make_float4(0.f, 0.f, 0.f, 0.f);
                if (n < NN) v = *(const float4*)(x + (size_t)n * 64 + p * 32 + kq * 4);
                xt[kq * 4 + 0][node] = v.x;
                xt[kq * 4 + 1][node] = v.y;
                xt[kq * 4 + 2][node] = v.z;
                xt[kq * 4 + 3][node] = v.w;
            }
            __syncthreads();
            #pragma unroll 4
            for (int k = 0; k < 32; k++) {
                float4 xv = *(const float4*)&xt[k][ng * 4];
                #pragma unroll
                for (int i = 0; i < 5; i++) {
                    float4 wv = wl4[k * 40 + qg + 8 * i];
                    acc[0][i][0] += xv.x * wv.x; acc[0][i][1] += xv.x * wv.y;
                    acc[0][i][2] += xv.x * wv.z; acc[0][i][3] += xv.x * wv.w;
                    acc[1][i][0] += xv.y * wv.x; acc[1][i][1] += xv.y * wv.y;
                    acc[1][i][2] += xv.y * wv.z; acc[1][i][3] += xv.y * wv.w;
                    acc[2][i][0] += xv.z * wv.x; acc[2][i][1] += xv.z * wv.y;
                    acc[2][i][2] += xv.z * wv.z; acc[2][i][3] += xv.z * wv.w;
                    acc[3][i][0] += xv.w * wv.x; acc[3][i][1] += xv.w * wv.y;
                    acc[3][i][2] += xv.w * wv.z; acc[3][i][3] += xv.w * wv.w;
                }
            }
        }
        #pragma unroll
        for (int i = 0; i < 5; i++) {
            int j0 = (qg + 8 * i) * 4;
            float4 bv = *(const float4*)(b1 + j0);
            #pragma unroll
            for (int r = 0; r < 4; r++) {
                int node = ng * 4 + r;
                float v0 = acc[r][i][0] + bv.x; v0 = v0 > 0.f ? v0 : 0.f;
                float v1 = acc[r][i][1] + bv.y; v1 = v1 > 0.f ? v1 : 0.f;
                float v2 = acc[r][i][2] + bv.z; v2 = v2 > 0.f ? v2 : 0.f;
                float v3 = acc[r][i][3] + bv.w; v3 = v3 > 0.f ? v3 : 0.f;
                y[j0 + 0][node] = __float2half_rn(v0);
                y[j0 + 1][node] = __float2half_rn(v1);
                y[j0 + 2][node] = __float2half_rn(v2);
                y[j0 + 3][node] = __float2half_rn(v3);
            }
        }
    }
    __syncthreads();

    {
        int qg = t & 15, ng = t >> 4;
        float acc[8][4] = {};
        #pragma unroll
        for (int p = 0; p < 2; p++) {
            if (p) __syncthreads();
            for (int i = t; i < 80 * 64 / 4; i += 256)
                ((float4*)wl)[i] = ((const float4*)W2)[p * 80 * 16 + i];
            __syncthreads();
            #pragma unroll 2
            for (int k = 0; k < 80; k++) {
                float4 wv = wl4[k * 16 + qg];
                uint4 yr = *(const uint4*)&y[p * 80 + k][ng * 8];
                float2 f0 = __half22float2(*(__half2*)&yr.x);
                float2 f1 = __half22float2(*(__half2*)&yr.y);
                float2 f2 = __half22float2(*(__half2*)&yr.z);
                float2 f3 = __half22float2(*(__half2*)&yr.w);
                acc[0][0] += f0.x * wv.x; acc[0][1] += f0.x * wv.y;
                acc[0][2] += f0.x * wv.z; acc[0][3] += f0.x * wv.w;
                acc[1][0] += f0.y * wv.x; acc[1][1] += f0.y * wv.y;
                acc[1][2] += f0.y * wv.z; acc[1][3] += f0.y * wv.w;
                acc[2][0] += f1.x * wv.x; acc[2][1] += f1.x * wv.y;
                acc[2][2] += f1.x * wv.z; acc[2][3] += f1.x * wv.w;
                acc[3][0] += f1.y * wv.x; acc[3][1] += f1.y * wv.y;
                acc[3][2] += f1.y * wv.z; acc[3][3] += f1.y * wv.w;
                acc[4][0] += f2.x * wv.x; acc[4][1] += f2.x * wv.y;
                acc[4][2] += f2.x * wv.z; acc[4][3] += f2.x * wv.w;
                acc[5][0] += f2.y * wv.x; acc[5][1] += f2.y * wv.y;
                acc[5][2] += f2.y * wv.z; acc[5][3] += f2.y * wv.w;
                acc[6][0] += f3.x * wv.x; acc[6][1] += f3.x * wv.y;
                acc[6][2] += f3.x * wv.z; acc[6][3] += f3.x * wv.w;
                acc[7][0] += f3.y * wv.x; acc[7][1] += f3.y * wv.y;
                acc[7][2] += f3.y * wv.z; acc[7][3] += f3.y * wv.w;
            }
        }
        int j0 = qg * 4;
        float4 bv = *(const float4*)(b2 + j0);
        #pragma unroll
        for (int r = 0; r < 8; r++) {
            int n = nb + ng * 8 + r;
            if (n < NN) {
                float4 o;
                o.x = acc[r][0] + bv.x; o.y = acc[r][1] + bv.y;
                o.z = acc[r][2] + bv.z; o.w = acc[r][3] + bv.w;
                *(float4*)(out + (size_t)n * 64 + j0) = o;
            }
        }
    }
}

// ---------------- launch ----------------

extern "C" void kernel_launch(void* const* d_in, const int* in_sizes, int n_in,
                              void* d_out, int out_size, void* d_ws, size_t ws_size,
                              hipStream_t stream) {
    const float* x   = (const float*)d_in[0];
    const int*   ei  = (const int*)d_in[1];
    const float* W0  = (const float*)d_in[2];
    const float* as0 = (const float*)d_in[3];
    const float* ad0 = (const float*)d_in[4];
    const float* b0  = (const float*)d_in[5];
    const float* W1  = (const float*)d_in[6];
    const float* as1 = (const float*)d_in[7];
    const float* ad1 = (const float*)d_in[8];
    const float* b1  = (const float*)d_in[9];
    const float* W2  = (const float*)d_in[10];
    const float* as2 = (const float*)d_in[11];
    const float* ad2 = (const float*)d_in[12];
    const float* b2  = (const float*)d_in[13];
    const float* fw1 = (const float*)d_in[14];
    const float* fb1 = (const float*)d_in[15];
    const float* fw2 = (const float*)d_in[16];
    const float* fb2 = (const float*)d_in[17];

    float* ws = (float*)d_ws;
    __half* hA  = (__half*)ws;                       // N*64 halves = N*32 floats
    __half* hB  = (__half*)(ws + (size_t)NN * 32);   // N*32 floats
    float* sAsrc = ws + (size_t)NN * 64;             // N*4
    float* sAdst = sAsrc + (size_t)NN * NHEADS;      // N*4
    float* sBsrc = sAdst + (size_t)NN * NHEADS;      // N*4
    float* sBdst = sBsrc + (size_t)NN * NHEADS;      // N*4
    float* act   = sBdst + (size_t)NN * NHEADS;      // N*64
    float* scr   = act + (size_t)NN * HIDD;          // CSR scratch region
    unsigned* binned = (unsigned*)scr;               // NBKT*BSTRIDE ~1.0M
    int*   csrc   = (int*)scr + 1100000;             // NBKT*BSTRIDE ~1.0M
    int*   rowbeg = (int*)scr + 2200000;             // NN
    int*   rowend = (int*)scr + 2300000;             // NN
    int*   cursor = (int*)scr + 2400000;             // NBKT

    k_zero<<<1, 256, 0, stream>>>(cursor);
    k_binwrite<<<NEBLK, 256, 0, stream>>>(ei, cursor, binned);
    k_csr_final<<<NBKT, 256, 0, stream>>>(cursor, binned, rowbeg, rowend, csrc);

    // layer 0 GEMM: x @ W0 -> hA, sA
    k_gemm_scores<128><<<NGB, 256, 0, stream>>>(x, W0, as0, ad0, hA, sAsrc, sAdst);
    // fused: aggr(layer0) + gemm(layer1) -> hB, sB
    k_aggr_gemm<<<NGB, 512, 0, stream>>>(hA, sAsrc, sAdst, rowbeg, rowend, csrc,
                                         b0, W1, as1, ad1, hB, sBsrc, sBdst);
    // fused: aggr(layer1) + gemm(layer2) -> hA, sA
    k_aggr_gemm<<<NGB, 512, 0, stream>>>(hB, sBsrc, sBdst, rowbeg, rowend, csrc,
                                         b1, W2, as2, ad2, hA, sAsrc, sAdst);
    // final aggregation -> act
    k_aggr<<<NN / 4, 256, 0, stream>>>(hA, sAsrc, sAdst, rowbeg, rowend, csrc, b2, act);

    // fused FC head
    k_fc_fused<<<NFC128, 256, 0, stream>>>(act, fw1, fb1, fw2, fb2, (float*)d_out);
}